// Round 4
// baseline (175.106 us; speedup 1.0000x reference)
//
#include <hip/hip_runtime.h>

// Shapes: B=2, F=T=2048, HIDDEN=1024, HEADS=16, DEPTH=64
#define LOG2E 1.44269504f

typedef __attribute__((ext_vector_type(8))) short short8v;  // 8 bf16
typedef __attribute__((ext_vector_type(4))) float f32x4;
typedef unsigned int u32;
typedef __attribute__((address_space(1))) const u32* gp_t;
typedef __attribute__((address_space(3))) u32* lp_t;

#define MFMA(a, b, c) __builtin_amdgcn_mfma_f32_16x16x32_bf16((a), (b), (c), 0, 0, 0)

__device__ __forceinline__ unsigned short f2bf(float f) {  // RNE fp32->bf16
  unsigned int u = __float_as_uint(f);
  u = (u + 0x7fffu + ((u >> 16) & 1u)) >> 16;
  return (unsigned short)u;
}
__device__ __forceinline__ u32 cvtpk(float lo, float hi) {  // HW RNE pack (T12)
  u32 r;
  asm("v_cvt_pk_bf16_f32 %0, %1, %2" : "=v"(r) : "v"(lo), "v"(hi));
  return r;
}
__device__ __forceinline__ float max3f(float a, float b, float c) {
  return fmaxf(fmaxf(a, b), c);  // fuses to v_max3_f32
}

// ---------------- fp32 -> bf16 convert (x4 vectorized) ----------------
__global__ void k_cvt(const float* __restrict__ in, unsigned short* __restrict__ out,
                      int n4, float scale) {
  int stride = gridDim.x * blockDim.x;
  for (int i = blockIdx.x * blockDim.x + threadIdx.x; i < n4; i += stride) {
    float4 v = reinterpret_cast<const float4*>(in)[i];
    ushort4 o;
    o.x = f2bf(v.x * scale); o.y = f2bf(v.y * scale);
    o.z = f2bf(v.z * scale); o.w = f2bf(v.w * scale);
    reinterpret_cast<ushort4*>(out)[i] = o;
  }
}

// ------------- transpose+convert 1024x1024 weight: out[j][i] = in[i][j]*scale -------------
__global__ void k_cvt_t(const float* __restrict__ in, unsigned short* __restrict__ out,
                        float scale) {
  __shared__ float tile[32][33];
  int bx = blockIdx.x * 32, by = blockIdx.y * 32;
  int tx = threadIdx.x, ty = threadIdx.y;  // block (32,8)
  for (int r = ty; r < 32; r += 8)
    tile[r][tx] = in[(size_t)(by + r) * 1024 + bx + tx];
  __syncthreads();
  for (int r = ty; r < 32; r += 8)
    out[(size_t)(bx + r) * 1024 + by + tx] = f2bf(tile[tx][r] * scale);
}

// ---- bias permute to f32 MFMA C-fragment layout, *LOG2E (coalesced writes) ----
// dest float idx: ((fb*32+ch)*4 + tt)*256 + (g*16+l15)*4 + r
//   <- bias[fb*16+l15][ch*64 + tt*16 + g*4 + r] * LOG2E
__global__ void k_bias_perm(const float* __restrict__ in, float* __restrict__ out) {
  int bid = blockIdx.x;                 // fb*32 + ch, grid 4096
  int fb = bid >> 5, ch = bid & 31;
  int tid = threadIdx.x;
  int tt = tid >> 6, rem = tid & 63;
  int g = rem >> 4, l15 = rem & 15;
  float4 v = *reinterpret_cast<const float4*>(
      &in[(size_t)(fb * 16 + l15) * 2048 + ch * 64 + tt * 16 + g * 4]);
  v.x *= LOG2E; v.y *= LOG2E; v.z *= LOG2E; v.w *= LOG2E;
  *reinterpret_cast<float4*>(&out[(size_t)bid * 1024 + tid * 4]) = v;
}

// ------------- bf16 GEMM: C[4096][N] = A[4096][1024] * BT[N][1024]^T -------------
// BM=128, BN=NF*32, BK=64; 4 waves (2x2), wave tile 64 x (NF*16).
// Single-buffered LDS (m97 structure), gload_lds width-16, XOR swizzle, 2 barriers/K-step.
// mode 0: bf16 -> [b][head][s][64] ; mode 2: f32 row-major
// mode 3: fused KV: col<1024 -> K layout (dst), col>=1024 -> V^T layout (dst2)
template <int NF>
__global__ __launch_bounds__(256)
void k_gemm(const unsigned short* __restrict__ A, const unsigned short* __restrict__ BT,
            void* dst, void* dst2, int mode) {
  __shared__ __align__(16) unsigned short Al[128 * 64];
  __shared__ __align__(16) unsigned short Bl[NF * 32 * 64];
  const int tid = threadIdx.x;
  const int lane = tid & 63, wid = tid >> 6;
  const int g = lane >> 4, l15 = lane & 15, l7 = l15 & 7;
  const int wm = wid >> 1, wn = wid & 1;
  const int rowbase = blockIdx.y * 128, colbase = blockIdx.x * (NF * 32);
  const int xgl = (g ^ l7) << 4;

  // staging: chunk cid -> row cid>>3, phys col-chunk cid&7 holds logical (cid&7)^(row&7)
  const int jr = tid >> 3;
  const int sc = ((tid & 7) ^ (jr & 7)) << 3;

  const f32x4 zf = {0.f, 0.f, 0.f, 0.f};
  f32x4 acc[4][NF];
#pragma unroll
  for (int m = 0; m < 4; ++m)
#pragma unroll
    for (int n = 0; n < NF; ++n) acc[m][n] = zf;

  char* Ad = (char*)Al;
  char* Bd = (char*)Bl;
  const char* Ac = (const char*)Al;
  const char* Bc = (const char*)Bl;

#pragma unroll 1
  for (int k0 = 0; k0 < 1024; k0 += 64) {
#pragma unroll
    for (int p = 0; p < 4; ++p) {  // A: 128 rows
      const unsigned short* src = A + (size_t)(rowbase + jr + p * 32) * 1024 + k0 + sc;
      __builtin_amdgcn_global_load_lds((gp_t)src, (lp_t)(Ad + (p * 256 + tid) * 16), 16, 0, 0);
    }
#pragma unroll
    for (int p = 0; p < NF; ++p) {  // B: NF*32 rows
      const unsigned short* src = BT + (size_t)(colbase + jr + p * 32) * 1024 + k0 + sc;
      __builtin_amdgcn_global_load_lds((gp_t)src, (lp_t)(Bd + (p * 256 + tid) * 16), 16, 0, 0);
    }
    __syncthreads();
#pragma unroll
    for (int kk = 0; kk < 2; ++kk) {
      short8v af[4], bfr[NF];
#pragma unroll
      for (int m = 0; m < 4; ++m)
        af[m] = *reinterpret_cast<const short8v*>(
            Ac + ((wm * 64 + m * 16 + l15) << 7) + (xgl ^ (kk << 6)));
#pragma unroll
      for (int n = 0; n < NF; ++n)
        bfr[n] = *reinterpret_cast<const short8v*>(
            Bc + ((wn * (NF * 16) + n * 16 + l15) << 7) + (xgl ^ (kk << 6)));
#pragma unroll
      for (int m = 0; m < 4; ++m)
#pragma unroll
        for (int n = 0; n < NF; ++n) acc[m][n] = MFMA(af[m], bfr[n], acc[m][n]);
    }
    __syncthreads();
  }

#pragma unroll
  for (int m = 0; m < 4; ++m)
#pragma unroll
    for (int n = 0; n < NF; ++n)
#pragma unroll
      for (int r = 0; r < 4; ++r) {
        int row = rowbase + wm * 64 + m * 16 + g * 4 + r;   // C/D: row=(lane>>4)*4+reg
        int col = colbase + wn * (NF * 16) + n * 16 + l15;  //      col=lane&15
        float v = acc[m][n][r];
        if (mode == 2) {
          reinterpret_cast<float*>(dst)[(size_t)row * 1024 + col] = v;
        } else {
          int b = row >> 11, s = row & 2047;
          if (mode == 0 || col < 1024) {
            int hd = col >> 6, h = col & 63;
            reinterpret_cast<unsigned short*>(dst)[((size_t)(b * 16 + hd) * 2048 + s) * 64 + h] =
                f2bf(v);
          } else {
            int c2 = col - 1024;
            int hd = c2 >> 6, h = c2 & 63;
            reinterpret_cast<unsigned short*>(dst2)[((size_t)(b * 16 + hd) * 64 + h) * 2048 + s] =
                f2bf(v);
          }
        }
      }
}

// ---------------- flash attention, transposed-S, dbuf + gload_lds + swizzle ----------------
// block = (f-tile 64, one (b,head)); 4 waves x 16 f-rows. 1 barrier/chunk.
__global__ __launch_bounds__(256, 4)
void k_attn(const unsigned short* __restrict__ qw,    // [B*N][F][64] (* scale * log2e)
            const unsigned short* __restrict__ kw,    // [B*N][T][64]
            const unsigned short* __restrict__ vtw,   // [B*N][64][T]
            const float* __restrict__ biaspf,         // f32 C-frag layout (* log2e)
            unsigned short* __restrict__ attnb) {     // [B][F][N*64] bf16
  __shared__ __align__(16) unsigned short Kl[2][4096];
  __shared__ __align__(16) unsigned short Vl[2][4096];
  __shared__ __align__(16) unsigned short Pl[4][1024];

  const int tid = threadIdx.x;
  const int lane = tid & 63, wid = tid >> 6;
  const int g = lane >> 4, l15 = lane & 15, l7 = l15 & 7;
  const int xgl = (g ^ l7) << 4;

  const int bid = blockIdx.x;  // ft-major: 32 consecutive blocks share a bias slab
  const int ft = bid >> 5, bn = bid & 31;
  const int b = bn >> 4, n = bn & 15;

  const size_t hoff = (size_t)bn * (2048 * 64);
  const unsigned short* qp = qw + hoff;
  const unsigned short* kp = kw + hoff;
  const unsigned short* vp = vtw + hoff;

  const int f0 = ft * 64 + wid * 16;
  const int fb = ft * 4 + wid;

  // staging sources (pre-swizzled)
  const int jr = tid >> 3;
  const int sc = ((tid & 7) ^ (jr & 7)) << 3;
  const unsigned short* Ks0 = kp + jr * 64 + sc;
  const unsigned short* Ks1 = kp + (jr + 32) * 64 + sc;
  const unsigned short* Vs0 = vp + jr * 2048 + sc;
  const unsigned short* Vs1 = vp + (jr + 32) * 2048 + sc;
  char* K0d = (char*)&Kl[0][0]; char* K1d = (char*)&Kl[1][0];
  char* V0d = (char*)&Vl[0][0]; char* V1d = (char*)&Vl[1][0];

  auto stage = [&](char* Kd, char* Vd, int ci) {
    int ko = ci << 12, vo = ci << 6;
    __builtin_amdgcn_global_load_lds((gp_t)(Ks0 + ko), (lp_t)(Kd + tid * 16), 16, 0, 0);
    __builtin_amdgcn_global_load_lds((gp_t)(Ks1 + ko), (lp_t)(Kd + 4096 + tid * 16), 16, 0, 0);
    __builtin_amdgcn_global_load_lds((gp_t)(Vs0 + vo), (lp_t)(Vd + tid * 16), 16, 0, 0);
    __builtin_amdgcn_global_load_lds((gp_t)(Vs1 + vo), (lp_t)(Vd + 4096 + tid * 16), 16, 0, 0);
  };

  // Q as B-fragment (col = f = f0+l15)
  short8v aq0 = *reinterpret_cast<const short8v*>(&qp[(size_t)(f0 + l15) * 64 + g * 8]);
  short8v aq1 = *reinterpret_cast<const short8v*>(&qp[(size_t)(f0 + l15) * 64 + 32 + g * 8]);

  const float* bias_lane = biaspf + (size_t)fb * 32768 + lane * 4;

  const f32x4 zf = {0.f, 0.f, 0.f, 0.f};
  f32x4 o[4];
  o[0] = zf; o[1] = zf; o[2] = zf; o[3] = zf;
  float ms = -1e30f, ls = 0.f;
  char* Pbl = (char*)&Pl[wid][0] + l15 * 128;

  auto bload = [&](int ci, f32x4* bc) {
#pragma unroll
    for (int tt = 0; tt < 4; ++tt)
      bc[tt] = *reinterpret_cast<const f32x4*>(bias_lane + ci * 1024 + tt * 256);
  };

  auto compute = [&](const unsigned short* Kb, const unsigned short* Vb, const f32x4* bc) {
    const char* Kc = (const char*)Kb; const char* Vc = (const char*)Vb;
    f32x4 st[4];
    __builtin_amdgcn_s_setprio(1);
#pragma unroll
    for (int tt = 0; tt < 4; ++tt) {
      short8v kb0 = *reinterpret_cast<const short8v*>(Kc + ((tt * 16 + l15) << 7) + xgl);
      short8v kb1 = *reinterpret_cast<const short8v*>(Kc + ((tt * 16 + l15) << 7) + (xgl ^ 64));
      st[tt] = MFMA(kb1, aq1, MFMA(kb0, aq0, bc[tt]));
    }
    __builtin_amdgcn_s_setprio(0);

    // tile max via v_max3 chains (16 values -> 8 ops)
    float m0 = max3f(st[0][0], st[0][1], st[0][2]);
    float m1 = max3f(st[0][3], st[1][0], st[1][1]);
    float m2 = max3f(st[1][2], st[1][3], st[2][0]);
    float m3 = max3f(st[2][1], st[2][2], st[2][3]);
    float m4 = max3f(st[3][0], st[3][1], st[3][2]);
    float tm = max3f(max3f(m0, m1, m2), max3f(m3, m4, st[3][3]),
                     __shfl_xor(max3f(m0, m1, m2), 16));  // placeholder; real reduce below
    tm = max3f(m0, m1, m2);
    tm = max3f(tm, m3, m4);
    tm = fmaxf(tm, st[3][3]);
    tm = fmaxf(tm, __shfl_xor(tm, 16));
    tm = fmaxf(tm, __shfl_xor(tm, 32));

    if (__any(tm > ms + 8.0f)) {  // defer-max (T13), exp2 domain
      float mn = fmaxf(ms, tm);
      float sca = __builtin_amdgcn_exp2f(ms - mn);
      ms = mn; ls *= sca;
      float s0 = __shfl(sca, g * 4 + 0, 16);
      float s1 = __shfl(sca, g * 4 + 1, 16);
      float s2 = __shfl(sca, g * 4 + 2, 16);
      float s3 = __shfl(sca, g * 4 + 3, 16);
#pragma unroll
      for (int ht = 0; ht < 4; ++ht) {
        o[ht][0] *= s0; o[ht][1] *= s1; o[ht][2] *= s2; o[ht][3] *= s3;
      }
    }

    float rs = 0.f;
#pragma unroll
    for (int tt = 0; tt < 4; ++tt) {
      float p0 = __builtin_amdgcn_exp2f(st[tt][0] - ms);
      float p1 = __builtin_amdgcn_exp2f(st[tt][1] - ms);
      float p2 = __builtin_amdgcn_exp2f(st[tt][2] - ms);
      float p3 = __builtin_amdgcn_exp2f(st[tt][3] - ms);
      rs += (p0 + p1) + (p2 + p3);
      uint2 w;
      w.x = cvtpk(p0, p1);
      w.y = cvtpk(p2, p3);
      *reinterpret_cast<uint2*>(Pbl + ((tt * 32 + g * 8) ^ (l7 * 16))) = w;
    }
    rs += __shfl_xor(rs, 16);
    rs += __shfl_xor(rs, 32);
    ls += rs;

    __builtin_amdgcn_s_setprio(1);
#pragma unroll
    for (int c = 0; c < 2; ++c) {
      short8v pa = *reinterpret_cast<const short8v*>(Pbl + ((c << 6) ^ xgl));
#pragma unroll
      for (int ht = 0; ht < 4; ++ht) {
        short8v vb = *reinterpret_cast<const short8v*>(
            Vc + ((ht * 16 + l15) << 7) + (xgl ^ (c << 6)));
        o[ht] = MFMA(pa, vb, o[ht]);
      }
    }
    __builtin_amdgcn_s_setprio(0);
  };

  f32x4 cb[4], nb[4];
  stage(K0d, V0d, 0);
  bload(0, cb);
  __syncthreads();
#pragma unroll 1
  for (int ci = 0; ci < 32; ci += 2) {
    stage(K1d, V1d, (ci + 1) & 31);
    bload((ci + 1) & 31, nb);
    compute(Kl[0], Vl[0], cb);
#pragma unroll
    for (int q = 0; q < 4; ++q) cb[q] = nb[q];
    __syncthreads();
    stage(K0d, V0d, (ci + 2) & 31);
    bload((ci + 2) & 31, nb);
    compute(Kl[1], Vl[1], cb);
#pragma unroll
    for (int q = 0; q < 4; ++q) cb[q] = nb[q];
    __syncthreads();
  }

  float inv = 1.f / ls;
  float i0 = __shfl(inv, g * 4 + 0, 16);
  float i1 = __shfl(inv, g * 4 + 1, 16);
  float i2 = __shfl(inv, g * 4 + 2, 16);
  float i3 = __shfl(inv, g * 4 + 3, 16);
#pragma unroll
  for (int ht = 0; ht < 4; ++ht) {
    unsigned short* ob = &attnb[((size_t)b * 2048 + f0 + g * 4) * 1024 + n * 64 + ht * 16 + l15];
    ob[0] = f2bf(o[ht][0] * i0);
    ob[1024] = f2bf(o[ht][1] * i1);
    ob[2048] = f2bf(o[ht][2] * i2);
    ob[3072] = f2bf(o[ht][3] * i3);
  }
}

extern "C" void kernel_launch(void* const* d_in, const int* in_sizes, int n_in,
                              void* d_out, int out_size, void* d_ws, size_t ws_size,
                              hipStream_t stream) {
  const float* query  = (const float*)d_in[0];
  const float* source = (const float*)d_in[1];
  const float* bias   = (const float*)d_in[2];
  const float* wq     = (const float*)d_in[3];
  const float* wk     = (const float*)d_in[4];
  const float* wv     = (const float*)d_in[5];
  const float* wo     = (const float*)d_in[6];

  char* ws = (char*)d_ws;  // 64 MB total
  unsigned short* qin_b  = (unsigned short*)(ws + 0);         // [4096][1024] bf16
  unsigned short* src_b  = (unsigned short*)(ws + 8388608);   // [4096][1024]
  float*          bias_f = (float*)(ws + 0);                  // f32 16MB, ALIASES qin/src
                                                              // (written after proj GEMMs)
  unsigned short* wqT    = (unsigned short*)(ws + 16777216);  // [1024][1024] (*0.125*log2e)
  unsigned short* wkvT   = (unsigned short*)(ws + 18874368);  // [2048][1024] fused K|V
  unsigned short* woT    = (unsigned short*)(ws + 23068672);  // [1024][1024]
  unsigned short* q_ws   = (unsigned short*)(ws + 25165824);  // [32][2048][64]
  unsigned short* k_ws   = (unsigned short*)(ws + 33554432);  // [32][2048][64]
  unsigned short* vT_ws  = (unsigned short*)(ws + 41943040);  // [32][64][2048]
  unsigned short* attn_b = (unsigned short*)(ws + 50331648);  // [4096][1024]

  k_cvt<<<2048, 256, 0, stream>>>(query,  qin_b, 1048576, 1.0f);
  k_cvt<<<2048, 256, 0, stream>>>(source, src_b, 1048576, 1.0f);
  dim3 tb(32, 8);
  k_cvt_t<<<dim3(32, 32), tb, 0, stream>>>(wq, wqT, 0.125f * LOG2E);
  k_cvt_t<<<dim3(32, 32), tb, 0, stream>>>(wk, wkvT, 1.0f);
  k_cvt_t<<<dim3(32, 32), tb, 0, stream>>>(wv, wkvT + 1048576, 1.0f);
  k_cvt_t<<<dim3(32, 32), tb, 0, stream>>>(wo, woT, 1.0f);

  k_gemm<2><<<dim3(16, 32), 256, 0, stream>>>(qin_b, wqT, q_ws, q_ws, 0);     // Q proj
  k_gemm<4><<<dim3(16, 32), 256, 0, stream>>>(src_b, wkvT, k_ws, vT_ws, 3);   // K|V fused
  k_bias_perm<<<4096, 256, 0, stream>>>(bias, bias_f);  // reuses [0,16MB) after GEMMs read it
  k_attn<<<1024, 256, 0, stream>>>(q_ws, k_ws, vT_ws, bias_f, attn_b);
  k_gemm<2><<<dim3(16, 32), 256, 0, stream>>>(attn_b, woT, d_out, d_out, 2);  // out proj
}